// Round 6
// baseline (590.103 us; speedup 1.0000x reference)
//
#include <hip/hip_runtime.h>

#define HWc   262144   // 512*512
#define CGc   128
#define CHc   64
#define COc   32
#define NPIXc 524288   // B*H*W
#define TW 32
#define TH 8
#define HLW 38         // TW+6
#define HLH 14         // TH+6
#define HPX (HLW*HLH)  // 532

typedef _Float16 h2 __attribute__((ext_vector_type(2)));

__device__ __forceinline__ int refl(int p){
  if (p < 0) p = -p;
  else if (p >= 512) p = 1022 - p;
  return p;
}
__device__ __forceinline__ h2 as_h2(unsigned u){ union{unsigned u; h2 h;} x; x.u = u; return x.h; }
__device__ __forceinline__ unsigned as_u(h2 h){ union{unsigned u; h2 h;} x; x.h = h; return x.u; }
__device__ __forceinline__ unsigned pkh(float a, float b){
  h2 h; h.x = (_Float16)a; h.y = (_Float16)b; return as_u(h);
}
__device__ __forceinline__ float2 upk(unsigned u){
  h2 h = as_h2(u); return make_float2((float)h.x, (float)h.y);
}
// d = a.f16[0]*b.f16[0] + a.f16[1]*b.f16[1] + c   (v_dot2_f32_f16)
__device__ __forceinline__ float dot2h(unsigned a, unsigned b, float c){
  return __builtin_amdgcn_fdot2(as_h2(a), as_h2(b), c, false);
}
// acc += f16half(ab) * e   — one VOP3P v_fma_mix_f32 (identical math to cvt+fma)
__device__ __forceinline__ void mixlo(float& acc, unsigned ab, float e){
  asm("v_fma_mix_f32 %0, %1, %2, %0 op_sel:[0,0,0] op_sel_hi:[1,0,0]"
      : "+v"(acc) : "v"(ab), "v"(e));
}
__device__ __forceinline__ void mixhi(float& acc, unsigned ab, float e){
  asm("v_fma_mix_f32 %0, %1, %2, %0 op_sel:[1,0,0] op_sel_hi:[1,0,0]"
      : "+v"(acc) : "v"(ab), "v"(e));
}

// -------- K0: sigma, pack w_sn and wg to f16 pairs -----------------------------------
__global__ void k0_prep(const float* __restrict__ wbar, const float* __restrict__ u,
                        const float* __restrict__ wg,
                        unsigned* __restrict__ wsnb, unsigned* __restrict__ wgb){
  const int t = threadIdx.x;
  __shared__ float sv1[32];
  float tv = 0.f;
  if (t < 32){
    #pragma unroll
    for (int o = 0; o < 32; o++) tv += wbar[o*32 + t] * u[o];
  }
  float sq = tv * tv;
  #pragma unroll
  for (int off = 32; off; off >>= 1) sq += __shfl_down(sq, off);
  const float n1 = sqrtf(__shfl(sq, 0)) + 1e-12f;
  if (t < 32) sv1[t] = tv / n1;
  __syncthreads();
  float tu = 0.f;
  if (t < 32){
    #pragma unroll
    for (int c = 0; c < 32; c++) tu += wbar[t*32 + c] * sv1[c];
  }
  float sq2 = tu * tu;
  #pragma unroll
  for (int off = 32; off; off >>= 1) sq2 += __shfl_down(sq2, off);
  const float S = __shfl(sq2, 0);
  const float inv = (sqrtf(S) + 1e-12f) / S;     // 1/sigma
  for (int k = t; k < 512; k += 64){             // wsnb[o][p], 16 pairs per row
    const int o = k >> 4, p = k & 15;
    wsnb[k] = pkh(wbar[o*32 + 2*p] * inv, wbar[o*32 + 2*p + 1] * inv);
  }
  for (int k = t; k < 4096; k += 64){            // wgb[o][p], 64 pairs per row
    const int o = k >> 6, p = k & 63;
    wgb[k] = pkh(wg[o*128 + 2*p], wg[o*128 + 2*p + 1]);
  }
}

// -------- K1f: fused {1x1 conv 128->64 + L2 norm -> gn}  and  {alpha' = W_sn*alpha} --
__global__ __launch_bounds__(256) void k1f(const float* __restrict__ f,
                                           const float* __restrict__ alpha,
                                           const unsigned* __restrict__ wgb,
                                           const unsigned* __restrict__ wsnb,
                                           const float* __restrict__ bg,
                                           unsigned* __restrict__ gn,
                                           unsigned* __restrict__ apm){
  const int p   = blockIdx.x * 256 + threadIdx.x;
  const int b   = p >> 18;
  const int pix = p & (HWc - 1);
  const float* fb = f + (size_t)b * CGc * HWc + pix;

  // ---- gn = normalize(Wg f + bg) ----
  float acc[CHc];
  #pragma unroll
  for (int o = 0; o < CHc; o++) acc[o] = bg[o];

  #pragma unroll 1
  for (int pp = 0; pp < 64; pp += 4){
    unsigned fp[4];
    #pragma unroll
    for (int m = 0; m < 4; m++)
      fp[m] = pkh(fb[(size_t)(2*(pp+m)) * HWc], fb[(size_t)(2*(pp+m)+1) * HWc]);
    #pragma unroll
    for (int o = 0; o < CHc; o++){
      float a = acc[o];
      a = dot2h(fp[0], wgb[o*64 + pp + 0], a);
      a = dot2h(fp[1], wgb[o*64 + pp + 1], a);
      a = dot2h(fp[2], wgb[o*64 + pp + 2], a);
      a = dot2h(fp[3], wgb[o*64 + pp + 3], a);
      acc[o] = a;
    }
  }
  float nsq = 0.f;
  #pragma unroll
  for (int o = 0; o < CHc; o++) nsq = fmaf(acc[o], acc[o], nsq);
  const float inv = 1.f / fmaxf(sqrtf(nsq), 1e-4f);

  uint4* gp = (uint4*)(gn + (size_t)p * 32);
  #pragma unroll
  for (int k = 0; k < 8; k++){
    uint4 w;
    w.x = pkh(acc[8*k+0]*inv, acc[8*k+1]*inv);
    w.y = pkh(acc[8*k+2]*inv, acc[8*k+3]*inv);
    w.z = pkh(acc[8*k+4]*inv, acc[8*k+5]*inv);
    w.w = pkh(acc[8*k+6]*inv, acc[8*k+7]*inv);
    gp[k] = w;
  }

  // ---- apm = f16(W_sn * alpha), pixel-major ----
  const float* ab = alpha + (size_t)b * COc * HWc + pix;
  unsigned a16[16];
  #pragma unroll
  for (int k = 0; k < 16; k++)
    a16[k] = pkh(ab[(size_t)(2*k) * HWc], ab[(size_t)(2*k+1) * HWc]);
  unsigned ow[16];
  #pragma unroll
  for (int o = 0; o < COc; o += 2){
    float s0 = 0.f, s1 = 0.f;
    #pragma unroll
    for (int k = 0; k < 16; k++){
      s0 = dot2h(a16[k], wsnb[(o+0)*16 + k], s0);
      s1 = dot2h(a16[k], wsnb[(o+1)*16 + k], s1);
    }
    ow[o >> 1] = pkh(s0, s1);
  }
  uint4* op = (uint4*)(apm + (size_t)p * 16);
  #pragma unroll
  for (int k = 0; k < 4; k++)
    op[k] = make_uint4(ow[4*k], ow[4*k+1], ow[4*k+2], ow[4*k+3]);
}

// -------- K2: two-phase channel-split correlation + softmax + agg -> y2 f16 ----------
__global__ __launch_bounds__(256) void k2_agg(const unsigned* __restrict__ gn,
                                              const unsigned* __restrict__ apm,
                                              unsigned* __restrict__ y2){
  __shared__ uint4 gs4[4][HPX];   // 34 KB: ONE 32-channel half of the halo

  const int lb  = (blockIdx.x & 7) * 256 + (blockIdx.x >> 3);   // XCD-chunked swizzle
  const int txx = lb & 15;
  const int tyy = (lb >> 4) & 63;
  const int bb  = lb >> 10;
  const int x0  = txx * TW, y0 = tyy * TH;
  const int tid = threadIdx.x;

  const int r  = tid >> 5, c = tid & 31;
  const int yy = y0 + r,  xx = x0 + c;
  const int self = (r + 3) * HLW + (c + 3);

  // ---- stage half A (channels 0..31) ----
  for (int t = tid; t < HPX; t += 256){
    const int hr = t / HLW;
    const int hc = t - hr * HLW;
    const int gy = refl(y0 + hr - 3);
    const int gx = refl(x0 + hc - 3);
    const uint4* src = (const uint4*)(gn + (size_t)((bb << 18) + (gy << 9) + gx) * 32);
    #pragma unroll
    for (int k = 0; k < 4; k++) gs4[k][t] = src[k];
  }
  __syncthreads();

  uint4 cv[4];
  #pragma unroll
  for (int k = 0; k < 4; k++) cv[k] = gs4[k][self];

  // ---- phase A: partial scores over channels 0..31 (fully unrolled: sc[] static) ----
  float sc[49];
  #pragma unroll
  for (int i = 0; i < 7; i++){
    #pragma unroll
    for (int j = 0; j < 7; j++){
      if (i == 3 && j == 3) continue;
      const int hp = (r + i) * HLW + (c + j);
      float s0 = 0.f, s1 = 0.f, s2 = 0.f, s3 = 0.f;
      #pragma unroll
      for (int k = 0; k < 4; k++){
        const uint4 q = gs4[k][hp];
        s0 = dot2h(cv[k].x, q.x, s0);
        s1 = dot2h(cv[k].y, q.y, s1);
        s2 = dot2h(cv[k].z, q.z, s2);
        s3 = dot2h(cv[k].w, q.w, s3);
      }
      sc[i*7+j] = (s0 + s1) + (s2 + s3);
    }
  }
  __syncthreads();   // phase-A reads complete before restage

  // ---- stage half B (channels 32..63) ----
  for (int t = tid; t < HPX; t += 256){
    const int hr = t / HLW;
    const int hc = t - hr * HLW;
    const int gy = refl(y0 + hr - 3);
    const int gx = refl(x0 + hc - 3);
    const uint4* src = (const uint4*)(gn + (size_t)((bb << 18) + (gy << 9) + gx) * 32);
    #pragma unroll
    for (int k = 0; k < 4; k++) gs4[k][t] = src[k + 4];
  }
  __syncthreads();

  #pragma unroll
  for (int k = 0; k < 4; k++) cv[k] = gs4[k][self];

  int ax[7];
  #pragma unroll
  for (int j = 0; j < 7; j++) ax[j] = refl(xx + j - 3);

  float yac[COc];
  #pragma unroll
  for (int k = 0; k < COc; k++) yac[k] = 0.f;
  float esum = 0.f;

  // ---- phase B: finish scores, exp, aggregate alpha' ----
  #pragma unroll
  for (int i = 0; i < 7; i++){
    const int ay = refl(yy + i - 3);
    const unsigned* aprow = apm + (size_t)((bb << 18) + (ay << 9)) * 16;
    #pragma unroll
    for (int j = 0; j < 7; j++){
      if (i == 3 && j == 3) continue;          // center tap: exp(-10000) == 0
      const int hp = (r + i) * HLW + (c + j);
      float s0 = sc[i*7+j], s1 = 0.f, s2 = 0.f, s3 = 0.f;
      #pragma unroll
      for (int k = 0; k < 4; k++){
        const uint4 q = gs4[k][hp];
        s0 = dot2h(cv[k].x, q.x, s0);
        s1 = dot2h(cv[k].y, q.y, s1);
        s2 = dot2h(cv[k].z, q.z, s2);
        s3 = dot2h(cv[k].w, q.w, s3);
      }
      // |s|<=~1 (unit vectors): exp(s) directly == softmax with max folded out
      const float e = __expf((s0 + s1) + (s2 + s3));
      esum += e;
      const uint4* ap = (const uint4*)(aprow + (size_t)ax[j] * 16);
      #pragma unroll
      for (int kk = 0; kk < 4; kk++){
        const uint4 a = ap[kk];
        mixlo(yac[8*kk+0], a.x, e); mixhi(yac[8*kk+1], a.x, e);
        mixlo(yac[8*kk+2], a.y, e); mixhi(yac[8*kk+3], a.y, e);
        mixlo(yac[8*kk+4], a.z, e); mixhi(yac[8*kk+5], a.z, e);
        mixlo(yac[8*kk+6], a.w, e); mixhi(yac[8*kk+7], a.w, e);
      }
    }
  }

  const float inv = 1.f / esum;
  unsigned yw[16];
  #pragma unroll
  for (int k = 0; k < 16; k++) yw[k] = pkh(yac[2*k] * inv, yac[2*k+1] * inv);
  uint4* yp = (uint4*)(y2 + (size_t)((bb << 18) + (yy << 9) + xx) * 16);
  #pragma unroll
  for (int k = 0; k < 4; k++)
    yp[k] = make_uint4(yw[4*k], yw[4*k+1], yw[4*k+2], yw[4*k+3]);
}

// -------- K3: BN stats over f16 y2 ---------------------------------------------------
__global__ __launch_bounds__(256) void k3_stats(const unsigned* __restrict__ y2,
                                                float* __restrict__ stats){
  float s[COc], q[COc];
  #pragma unroll
  for (int o = 0; o < COc; o++){ s[o] = 0.f; q[o] = 0.f; }
  const int stride = gridDim.x * 256;
  for (int p = blockIdx.x * 256 + threadIdx.x; p < NPIXc; p += stride){
    const uint4* yp = (const uint4*)(y2 + (size_t)p * 16);
    #pragma unroll
    for (int k = 0; k < 4; k++){
      const uint4 w = yp[k];
      const unsigned vv[4] = {w.x, w.y, w.z, w.w};
      #pragma unroll
      for (int m = 0; m < 4; m++){
        const float2 ab = upk(vv[m]);
        s[8*k+2*m]   += ab.x; q[8*k+2*m]   = fmaf(ab.x, ab.x, q[8*k+2*m]);
        s[8*k+2*m+1] += ab.y; q[8*k+2*m+1] = fmaf(ab.y, ab.y, q[8*k+2*m+1]);
      }
    }
  }
  #pragma unroll
  for (int o = 0; o < COc; o++){
    #pragma unroll
    for (int off = 32; off; off >>= 1){
      s[o] += __shfl_down(s[o], off);
      q[o] += __shfl_down(q[o], off);
    }
  }
  __shared__ float red[4][64];
  const int wv = threadIdx.x >> 6;
  if ((threadIdx.x & 63) == 0){
    #pragma unroll
    for (int o = 0; o < COc; o++){ red[wv][o] = s[o]; red[wv][32 + o] = q[o]; }
  }
  __syncthreads();
  if (threadIdx.x < 64){
    const float v = red[0][threadIdx.x] + red[1][threadIdx.x]
                  + red[2][threadIdx.x] + red[3][threadIdx.x];
    atomicAdd(&stats[threadIdx.x], v);
  }
}

// -------- K3b: stats -> (mean, 0.1*rsqrt(var+eps)) ------------------------------------
__global__ void k3b_final(const float* __restrict__ stats, float* __restrict__ stats2){
  const int t = threadIdx.x;
  if (t < COc){
    const float invN = 1.f / (float)NPIXc;
    const float mean = stats[t] * invN;
    const float var  = fmaf(-mean, mean, stats[COc + t] * invN);
    stats2[t]       = mean;
    stats2[COc + t] = 0.1f * rsqrtf(var + 1e-5f);
  }
}

// -------- K4: BatchNorm + residual ----------------------------------------------------
__global__ __launch_bounds__(256) void k4_out(const unsigned* __restrict__ y2,
                                              const float* __restrict__ alpha,
                                              const float* __restrict__ stats2,
                                              float* __restrict__ out){
  const int p   = blockIdx.x * 256 + threadIdx.x;
  const int b   = p >> 18;
  const int pix = p & (HWc - 1);
  const uint4* yp = (const uint4*)(y2 + (size_t)p * 16);
  const size_t boff = (size_t)b * COc * HWc + pix;
  #pragma unroll
  for (int k = 0; k < 4; k++){
    const uint4 w = yp[k];
    const unsigned vv[4] = {w.x, w.y, w.z, w.w};
    #pragma unroll
    for (int m = 0; m < 4; m++){
      const int o = 8*k + 2*m;
      const float2 ab = upk(vv[m]);
      out[boff + (size_t)o*HWc]     = fmaf(ab.x - stats2[o],   stats2[COc+o],
                                           alpha[boff + (size_t)o*HWc]);
      out[boff + (size_t)(o+1)*HWc] = fmaf(ab.y - stats2[o+1], stats2[COc+o+1],
                                           alpha[boff + (size_t)(o+1)*HWc]);
    }
  }
}

extern "C" void kernel_launch(void* const* d_in, const int* in_sizes, int n_in,
                              void* d_out, int out_size, void* d_ws, size_t ws_size,
                              hipStream_t stream){
  const float* f     = (const float*)d_in[0];
  const float* alpha = (const float*)d_in[1];
  const float* wg    = (const float*)d_in[2];
  const float* bg    = (const float*)d_in[3];
  const float* wbar  = (const float*)d_in[4];
  const float* u     = (const float*)d_in[5];
  (void)in_sizes; (void)n_in; (void)out_size; (void)ws_size;
  float* out = (float*)d_out;

  char* ws = (char*)d_ws;
  float*    stats  = (float*)ws;                       // 256 B
  float*    stats2 = (float*)(ws + 4096);              // 256 B
  unsigned* wsnb   = (unsigned*)(ws + 8192);           // 2 KB
  unsigned* wgb    = (unsigned*)(ws + 16384);          // 16 KB
  unsigned* apm    = (unsigned*)(ws + 65536);                                   // 32 MB
  unsigned* gn     = (unsigned*)(ws + 65536 + (size_t)NPIXc*64);                // 64 MB
  unsigned* y2     = (unsigned*)(ws + 65536 + (size_t)NPIXc*64 + (size_t)NPIXc*128); // 32 MB

  hipMemsetAsync(stats, 0, 64 * sizeof(float), stream);
  k0_prep  <<<1, 64, 0, stream>>>(wbar, u, wg, wsnb, wgb);
  k1f      <<<NPIXc / 256, 256, 0, stream>>>(f, alpha, wgb, wsnb, bg, gn, apm);
  k2_agg   <<<2048, 256, 0, stream>>>(gn, apm, y2);
  k3_stats <<<256, 256, 0, stream>>>(y2, stats);
  k3b_final<<<1, 64, 0, stream>>>(stats, stats2);
  k4_out   <<<NPIXc / 256, 256, 0, stream>>>(y2, alpha, stats2, out);
}

// Round 7
// 412.708 us; speedup vs baseline: 1.4298x; 1.4298x over previous
//
#include <hip/hip_runtime.h>

#define HWc   262144   // 512*512
#define CGc   128
#define CHc   64
#define COc   32
#define NPIXc 524288   // B*H*W
#define TW 32
#define TH 8
#define HLW 38         // TW+6
#define HROWS 10       // circular row buffer (of 14 halo rows)
#define HPX (HLW*HROWS) // 380

typedef _Float16 h2 __attribute__((ext_vector_type(2)));

__device__ __forceinline__ int refl(int p){
  if (p < 0) p = -p;
  else if (p >= 512) p = 1022 - p;
  return p;
}
__device__ __forceinline__ h2 as_h2(unsigned u){ union{unsigned u; h2 h;} x; x.u = u; return x.h; }
__device__ __forceinline__ unsigned as_u(h2 h){ union{unsigned u; h2 h;} x; x.h = h; return x.u; }
__device__ __forceinline__ unsigned pkh(float a, float b){
  h2 h; h.x = (_Float16)a; h.y = (_Float16)b; return as_u(h);
}
__device__ __forceinline__ float2 upk(unsigned u){
  h2 h = as_h2(u); return make_float2((float)h.x, (float)h.y);
}
// d = a.f16[0]*b.f16[0] + a.f16[1]*b.f16[1] + c   (v_dot2_f32_f16)
__device__ __forceinline__ float dot2h(unsigned a, unsigned b, float c){
  return __builtin_amdgcn_fdot2(as_h2(a), as_h2(b), c, false);
}
// acc += f16half(ab) * e   — one VOP3P v_fma_mix_f32 (identical math to cvt+fma)
__device__ __forceinline__ void mixlo(float& acc, unsigned ab, float e){
  asm("v_fma_mix_f32 %0, %1, %2, %0 op_sel:[0,0,0] op_sel_hi:[1,0,0]"
      : "+v"(acc) : "v"(ab), "v"(e));
}
__device__ __forceinline__ void mixhi(float& acc, unsigned ab, float e){
  asm("v_fma_mix_f32 %0, %1, %2, %0 op_sel:[1,0,0] op_sel_hi:[1,0,0]"
      : "+v"(acc) : "v"(ab), "v"(e));
}

// -------- K0: sigma, pack w_sn and wg to f16 pairs -----------------------------------
__global__ void k0_prep(const float* __restrict__ wbar, const float* __restrict__ u,
                        const float* __restrict__ wg,
                        unsigned* __restrict__ wsnb, unsigned* __restrict__ wgb){
  const int t = threadIdx.x;
  __shared__ float sv1[32];
  float tv = 0.f;
  if (t < 32){
    #pragma unroll
    for (int o = 0; o < 32; o++) tv += wbar[o*32 + t] * u[o];
  }
  float sq = tv * tv;
  #pragma unroll
  for (int off = 32; off; off >>= 1) sq += __shfl_down(sq, off);
  const float n1 = sqrtf(__shfl(sq, 0)) + 1e-12f;
  if (t < 32) sv1[t] = tv / n1;
  __syncthreads();
  float tu = 0.f;
  if (t < 32){
    #pragma unroll
    for (int c = 0; c < 32; c++) tu += wbar[t*32 + c] * sv1[c];
  }
  float sq2 = tu * tu;
  #pragma unroll
  for (int off = 32; off; off >>= 1) sq2 += __shfl_down(sq2, off);
  const float S = __shfl(sq2, 0);
  const float inv = (sqrtf(S) + 1e-12f) / S;     // 1/sigma
  for (int k = t; k < 512; k += 64){             // wsnb[o][p], 16 pairs per row
    const int o = k >> 4, p = k & 15;
    wsnb[k] = pkh(wbar[o*32 + 2*p] * inv, wbar[o*32 + 2*p + 1] * inv);
  }
  for (int k = t; k < 4096; k += 64){            // wgb[o][p], 64 pairs per row
    const int o = k >> 6, p = k & 63;
    wgb[k] = pkh(wg[o*128 + 2*p], wg[o*128 + 2*p + 1]);
  }
}

// -------- K1f: fused {1x1 conv 128->64 + L2 norm -> gn}  and  {alpha' = W_sn*alpha} --
__global__ __launch_bounds__(256) void k1f(const float* __restrict__ f,
                                           const float* __restrict__ alpha,
                                           const unsigned* __restrict__ wgb,
                                           const unsigned* __restrict__ wsnb,
                                           const float* __restrict__ bg,
                                           unsigned* __restrict__ gn,
                                           unsigned* __restrict__ apm){
  const int p   = blockIdx.x * 256 + threadIdx.x;
  const int b   = p >> 18;
  const int pix = p & (HWc - 1);
  const float* fb = f + (size_t)b * CGc * HWc + pix;

  // ---- gn = normalize(Wg f + bg) ----
  float acc[CHc];
  #pragma unroll
  for (int o = 0; o < CHc; o++) acc[o] = bg[o];

  #pragma unroll 1
  for (int pp = 0; pp < 64; pp += 4){
    unsigned fp[4];
    #pragma unroll
    for (int m = 0; m < 4; m++)
      fp[m] = pkh(fb[(size_t)(2*(pp+m)) * HWc], fb[(size_t)(2*(pp+m)+1) * HWc]);
    #pragma unroll
    for (int o = 0; o < CHc; o++){
      float a = acc[o];
      a = dot2h(fp[0], wgb[o*64 + pp + 0], a);
      a = dot2h(fp[1], wgb[o*64 + pp + 1], a);
      a = dot2h(fp[2], wgb[o*64 + pp + 2], a);
      a = dot2h(fp[3], wgb[o*64 + pp + 3], a);
      acc[o] = a;
    }
  }
  float nsq = 0.f;
  #pragma unroll
  for (int o = 0; o < CHc; o++) nsq = fmaf(acc[o], acc[o], nsq);
  const float inv = 1.f / fmaxf(sqrtf(nsq), 1e-4f);

  uint4* gp = (uint4*)(gn + (size_t)p * 32);
  #pragma unroll
  for (int k = 0; k < 8; k++){
    uint4 w;
    w.x = pkh(acc[8*k+0]*inv, acc[8*k+1]*inv);
    w.y = pkh(acc[8*k+2]*inv, acc[8*k+3]*inv);
    w.z = pkh(acc[8*k+4]*inv, acc[8*k+5]*inv);
    w.w = pkh(acc[8*k+6]*inv, acc[8*k+7]*inv);
    gp[k] = w;
  }

  // ---- apm = f16(W_sn * alpha), pixel-major ----
  const float* ab = alpha + (size_t)b * COc * HWc + pix;
  unsigned a16[16];
  #pragma unroll
  for (int k = 0; k < 16; k++)
    a16[k] = pkh(ab[(size_t)(2*k) * HWc], ab[(size_t)(2*k+1) * HWc]);
  unsigned ow[16];
  #pragma unroll
  for (int o = 0; o < COc; o += 2){
    float s0 = 0.f, s1 = 0.f;
    #pragma unroll
    for (int k = 0; k < 16; k++){
      s0 = dot2h(a16[k], wsnb[(o+0)*16 + k], s0);
      s1 = dot2h(a16[k], wsnb[(o+1)*16 + k], s1);
    }
    ow[o >> 1] = pkh(s0, s1);
  }
  uint4* op = (uint4*)(apm + (size_t)p * 16);
  #pragma unroll
  for (int k = 0; k < 4; k++)
    op[k] = make_uint4(ow[4*k], ow[4*k+1], ow[4*k+2], ow[4*k+3]);
}

// -------- K2: row-sliced halo (10-row circular LDS) correlation+softmax+agg ----------
__global__ __launch_bounds__(256) void k2_agg(const unsigned* __restrict__ gn,
                                              const unsigned* __restrict__ apm,
                                              unsigned* __restrict__ y2){
  __shared__ uint4 gs4[8][HPX];   // 48640 B -> 3 blocks/CU

  const int lb  = (blockIdx.x & 7) * 256 + (blockIdx.x >> 3);   // XCD-chunked swizzle
  const int txx = lb & 15;
  const int tyy = (lb >> 4) & 63;
  const int bb  = lb >> 10;
  const int x0  = txx * TW, y0 = tyy * TH;
  const int tid = threadIdx.x;

  const int r  = tid >> 5, c = tid & 31;
  const int yy = y0 + r,  xx = x0 + c;

  // center vector: coalesced global read (wave reads 8KB contiguous, L2-hot)
  uint4 cv[8];
  {
    const uint4* cp = (const uint4*)(gn + (size_t)((bb << 18) + (yy << 9) + xx) * 32);
    #pragma unroll
    for (int k = 0; k < 8; k++) cv[k] = cp[k];
  }

  int ax[7];
  #pragma unroll
  for (int j = 0; j < 7; j++) ax[j] = refl(xx + j - 3);

  float yac[COc];
  #pragma unroll
  for (int k = 0; k < COc; k++) yac[k] = 0.f;
  float esum = 0.f;

  // ---- stage halo rows 0..9 ----
  for (int t = tid; t < HPX; t += 256){
    const int hr = t / HLW;
    const int hc = t - hr * HLW;
    const int gy = refl(y0 + hr - 3);
    const int gx = refl(x0 + hc - 3);
    const uint4* src = (const uint4*)(gn + (size_t)((bb << 18) + (gy << 9) + gx) * 32);
    #pragma unroll
    for (int k = 0; k < 8; k++) gs4[k][t] = src[k];
  }
  __syncthreads();

  // ---- phase 1: taps i = 0..2 (halo rows r+i <= 9, all staged) ----
  #pragma unroll 1
  for (int i = 0; i < 3; i++){
    const int ay = refl(yy + i - 3);
    const unsigned* aprow = apm + (size_t)((bb << 18) + (ay << 9)) * 16;
    const int rowbase = (r + i) * HLW + c;
    #pragma unroll
    for (int j = 0; j < 7; j++){
      const int hp = rowbase + j;
      float s0 = 0.f, s1 = 0.f, s2 = 0.f, s3 = 0.f;
      #pragma unroll
      for (int k = 0; k < 8; k++){
        const uint4 q = gs4[k][hp];
        s0 = dot2h(cv[k].x, q.x, s0);
        s1 = dot2h(cv[k].y, q.y, s1);
        s2 = dot2h(cv[k].z, q.z, s2);
        s3 = dot2h(cv[k].w, q.w, s3);
      }
      const float e = __expf((s0 + s1) + (s2 + s3));
      esum += e;
      const uint4* ap = (const uint4*)(aprow + (size_t)ax[j] * 16);
      #pragma unroll
      for (int kk = 0; kk < 4; kk++){
        const uint4 a = ap[kk];
        mixlo(yac[8*kk+0], a.x, e); mixhi(yac[8*kk+1], a.x, e);
        mixlo(yac[8*kk+2], a.y, e); mixhi(yac[8*kk+3], a.y, e);
        mixlo(yac[8*kk+4], a.z, e); mixhi(yac[8*kk+5], a.z, e);
        mixlo(yac[8*kk+6], a.w, e); mixhi(yac[8*kk+7], a.w, e);
      }
    }
  }
  __syncthreads();   // phase-1 reads of slots 0..3 complete

  // ---- restage halo rows 10..13 into slots 0..3 ----
  for (int t = tid; t < 4 * HLW; t += 256){
    const int hr = t / HLW;               // 0..3 -> halo rows 10..13
    const int hc = t - hr * HLW;
    const int gy = refl(y0 + hr + 7);     // (hr+10)-3
    const int gx = refl(x0 + hc - 3);
    const uint4* src = (const uint4*)(gn + (size_t)((bb << 18) + (gy << 9) + gx) * 32);
    #pragma unroll
    for (int k = 0; k < 8; k++) gs4[k][t] = src[k];
  }
  __syncthreads();

  // ---- phase 2: taps i = 3..6 (halo row r+i, slot = row mod 10) ----
  #pragma unroll 1
  for (int i = 3; i < 7; i++){
    const int ay = refl(yy + i - 3);
    const unsigned* aprow = apm + (size_t)((bb << 18) + (ay << 9)) * 16;
    const int hrow = r + i;
    const int rowbase = (hrow >= HROWS ? hrow - HROWS : hrow) * HLW + c;
    #pragma unroll
    for (int j = 0; j < 7; j++){
      if (i == 3 && j == 3) continue;      // center tap: exp(-10000) == 0
      const int hp = rowbase + j;
      float s0 = 0.f, s1 = 0.f, s2 = 0.f, s3 = 0.f;
      #pragma unroll
      for (int k = 0; k < 8; k++){
        const uint4 q = gs4[k][hp];
        s0 = dot2h(cv[k].x, q.x, s0);
        s1 = dot2h(cv[k].y, q.y, s1);
        s2 = dot2h(cv[k].z, q.z, s2);
        s3 = dot2h(cv[k].w, q.w, s3);
      }
      const float e = __expf((s0 + s1) + (s2 + s3));
      esum += e;
      const uint4* ap = (const uint4*)(aprow + (size_t)ax[j] * 16);
      #pragma unroll
      for (int kk = 0; kk < 4; kk++){
        const uint4 a = ap[kk];
        mixlo(yac[8*kk+0], a.x, e); mixhi(yac[8*kk+1], a.x, e);
        mixlo(yac[8*kk+2], a.y, e); mixhi(yac[8*kk+3], a.y, e);
        mixlo(yac[8*kk+4], a.z, e); mixhi(yac[8*kk+5], a.z, e);
        mixlo(yac[8*kk+6], a.w, e); mixhi(yac[8*kk+7], a.w, e);
      }
    }
  }

  const float inv = 1.f / esum;
  unsigned yw[16];
  #pragma unroll
  for (int k = 0; k < 16; k++) yw[k] = pkh(yac[2*k] * inv, yac[2*k+1] * inv);
  uint4* yp = (uint4*)(y2 + (size_t)((bb << 18) + (yy << 9) + xx) * 16);
  #pragma unroll
  for (int k = 0; k < 4; k++)
    yp[k] = make_uint4(yw[4*k], yw[4*k+1], yw[4*k+2], yw[4*k+3]);
}

// -------- K3: BN stats over f16 y2 ---------------------------------------------------
__global__ __launch_bounds__(256) void k3_stats(const unsigned* __restrict__ y2,
                                                float* __restrict__ stats){
  float s[COc], q[COc];
  #pragma unroll
  for (int o = 0; o < COc; o++){ s[o] = 0.f; q[o] = 0.f; }
  const int stride = gridDim.x * 256;
  for (int p = blockIdx.x * 256 + threadIdx.x; p < NPIXc; p += stride){
    const uint4* yp = (const uint4*)(y2 + (size_t)p * 16);
    #pragma unroll
    for (int k = 0; k < 4; k++){
      const uint4 w = yp[k];
      const unsigned vv[4] = {w.x, w.y, w.z, w.w};
      #pragma unroll
      for (int m = 0; m < 4; m++){
        const float2 ab = upk(vv[m]);
        s[8*k+2*m]   += ab.x; q[8*k+2*m]   = fmaf(ab.x, ab.x, q[8*k+2*m]);
        s[8*k+2*m+1] += ab.y; q[8*k+2*m+1] = fmaf(ab.y, ab.y, q[8*k+2*m+1]);
      }
    }
  }
  #pragma unroll
  for (int o = 0; o < COc; o++){
    #pragma unroll
    for (int off = 32; off; off >>= 1){
      s[o] += __shfl_down(s[o], off);
      q[o] += __shfl_down(q[o], off);
    }
  }
  __shared__ float red[4][64];
  const int wv = threadIdx.x >> 6;
  if ((threadIdx.x & 63) == 0){
    #pragma unroll
    for (int o = 0; o < COc; o++){ red[wv][o] = s[o]; red[wv][32 + o] = q[o]; }
  }
  __syncthreads();
  if (threadIdx.x < 64){
    const float v = red[0][threadIdx.x] + red[1][threadIdx.x]
                  + red[2][threadIdx.x] + red[3][threadIdx.x];
    atomicAdd(&stats[threadIdx.x], v);
  }
}

// -------- K3b: stats -> (mean, 0.1*rsqrt(var+eps)) ------------------------------------
__global__ void k3b_final(const float* __restrict__ stats, float* __restrict__ stats2){
  const int t = threadIdx.x;
  if (t < COc){
    const float invN = 1.f / (float)NPIXc;
    const float mean = stats[t] * invN;
    const float var  = fmaf(-mean, mean, stats[COc + t] * invN);
    stats2[t]       = mean;
    stats2[COc + t] = 0.1f * rsqrtf(var + 1e-5f);
  }
}

// -------- K4: BatchNorm + residual ----------------------------------------------------
__global__ __launch_bounds__(256) void k4_out(const unsigned* __restrict__ y2,
                                              const float* __restrict__ alpha,
                                              const float* __restrict__ stats2,
                                              float* __restrict__ out){
  const int p   = blockIdx.x * 256 + threadIdx.x;
  const int b   = p >> 18;
  const int pix = p & (HWc - 1);
  const uint4* yp = (const uint4*)(y2 + (size_t)p * 16);
  const size_t boff = (size_t)b * COc * HWc + pix;
  #pragma unroll
  for (int k = 0; k < 4; k++){
    const uint4 w = yp[k];
    const unsigned vv[4] = {w.x, w.y, w.z, w.w};
    #pragma unroll
    for (int m = 0; m < 4; m++){
      const int o = 8*k + 2*m;
      const float2 ab = upk(vv[m]);
      out[boff + (size_t)o*HWc]     = fmaf(ab.x - stats2[o],   stats2[COc+o],
                                           alpha[boff + (size_t)o*HWc]);
      out[boff + (size_t)(o+1)*HWc] = fmaf(ab.y - stats2[o+1], stats2[COc+o+1],
                                           alpha[boff + (size_t)(o+1)*HWc]);
    }
  }
}

extern "C" void kernel_launch(void* const* d_in, const int* in_sizes, int n_in,
                              void* d_out, int out_size, void* d_ws, size_t ws_size,
                              hipStream_t stream){
  const float* f     = (const float*)d_in[0];
  const float* alpha = (const float*)d_in[1];
  const float* wg    = (const float*)d_in[2];
  const float* bg    = (const float*)d_in[3];
  const float* wbar  = (const float*)d_in[4];
  const float* u     = (const float*)d_in[5];
  (void)in_sizes; (void)n_in; (void)out_size; (void)ws_size;
  float* out = (float*)d_out;

  char* ws = (char*)d_ws;
  float*    stats  = (float*)ws;                       // 256 B
  float*    stats2 = (float*)(ws + 4096);              // 256 B
  unsigned* wsnb   = (unsigned*)(ws + 8192);           // 2 KB
  unsigned* wgb    = (unsigned*)(ws + 16384);          // 16 KB
  unsigned* apm    = (unsigned*)(ws + 65536);                                   // 32 MB
  unsigned* gn     = (unsigned*)(ws + 65536 + (size_t)NPIXc*64);                // 64 MB
  unsigned* y2     = (unsigned*)(ws + 65536 + (size_t)NPIXc*64 + (size_t)NPIXc*128); // 32 MB

  hipMemsetAsync(stats, 0, 64 * sizeof(float), stream);
  k0_prep  <<<1, 64, 0, stream>>>(wbar, u, wg, wsnb, wgb);
  k1f      <<<NPIXc / 256, 256, 0, stream>>>(f, alpha, wgb, wsnb, bg, gn, apm);
  k2_agg   <<<2048, 256, 0, stream>>>(gn, apm, y2);
  k3_stats <<<256, 256, 0, stream>>>(y2, stats);
  k3b_final<<<1, 64, 0, stream>>>(stats, stats2);
  k4_out   <<<NPIXc / 256, 256, 0, stream>>>(y2, alpha, stats2, out);
}

// Round 8
// 328.314 us; speedup vs baseline: 1.7974x; 1.2571x over previous
//
#include <hip/hip_runtime.h>

#define HWc   262144   // 512*512
#define CGc   128
#define CHc   64
#define COc   32
#define NPIXc 524288   // B*H*W
#define TW 32
#define TH 8
#define HLW 38         // TW+6
#define HLH 14         // TH+6
#define HPX (HLW*HLH)  // 532

typedef _Float16 h2 __attribute__((ext_vector_type(2)));

__device__ __forceinline__ int refl(int p){
  if (p < 0) p = -p;
  else if (p >= 512) p = 1022 - p;
  return p;
}
__device__ __forceinline__ h2 as_h2(unsigned u){ union{unsigned u; h2 h;} x; x.u = u; return x.h; }
__device__ __forceinline__ unsigned as_u(h2 h){ union{unsigned u; h2 h;} x; x.h = h; return x.u; }
__device__ __forceinline__ unsigned pkh(float a, float b){
  h2 h; h.x = (_Float16)a; h.y = (_Float16)b; return as_u(h);
}
__device__ __forceinline__ float2 upk(unsigned u){
  h2 h = as_h2(u); return make_float2((float)h.x, (float)h.y);
}
// d = a.f16[0]*b.f16[0] + a.f16[1]*b.f16[1] + c   (v_dot2_f32_f16)
__device__ __forceinline__ float dot2h(unsigned a, unsigned b, float c){
  return __builtin_amdgcn_fdot2(as_h2(a), as_h2(b), c, false);
}
// acc += f16half(ab) * e   — one VOP3P v_fma_mix_f32 (identical math to cvt+fma)
__device__ __forceinline__ void mixlo(float& acc, unsigned ab, float e){
  asm("v_fma_mix_f32 %0, %1, %2, %0 op_sel:[0,0,0] op_sel_hi:[1,0,0]"
      : "+v"(acc) : "v"(ab), "v"(e));
}
__device__ __forceinline__ void mixhi(float& acc, unsigned ab, float e){
  asm("v_fma_mix_f32 %0, %1, %2, %0 op_sel:[1,0,0] op_sel_hi:[1,0,0]"
      : "+v"(acc) : "v"(ab), "v"(e));
}

// -------- K0: sigma, pack w_sn and wg to f16 pairs -----------------------------------
__global__ void k0_prep(const float* __restrict__ wbar, const float* __restrict__ u,
                        const float* __restrict__ wg,
                        unsigned* __restrict__ wsnb, unsigned* __restrict__ wgb){
  const int t = threadIdx.x;
  __shared__ float sv1[32];
  float tv = 0.f;
  if (t < 32){
    #pragma unroll
    for (int o = 0; o < 32; o++) tv += wbar[o*32 + t] * u[o];
  }
  float sq = tv * tv;
  #pragma unroll
  for (int off = 32; off; off >>= 1) sq += __shfl_down(sq, off);
  const float n1 = sqrtf(__shfl(sq, 0)) + 1e-12f;
  if (t < 32) sv1[t] = tv / n1;
  __syncthreads();
  float tu = 0.f;
  if (t < 32){
    #pragma unroll
    for (int c = 0; c < 32; c++) tu += wbar[t*32 + c] * sv1[c];
  }
  float sq2 = tu * tu;
  #pragma unroll
  for (int off = 32; off; off >>= 1) sq2 += __shfl_down(sq2, off);
  const float S = __shfl(sq2, 0);
  const float inv = (sqrtf(S) + 1e-12f) / S;     // 1/sigma
  for (int k = t; k < 512; k += 64){             // wsnb[o][p], 16 pairs per row
    const int o = k >> 4, p = k & 15;
    wsnb[k] = pkh(wbar[o*32 + 2*p] * inv, wbar[o*32 + 2*p + 1] * inv);
  }
  for (int k = t; k < 4096; k += 64){            // wgb[o][p], 64 pairs per row
    const int o = k >> 6, p = k & 63;
    wgb[k] = pkh(wg[o*128 + 2*p], wg[o*128 + 2*p + 1]);
  }
}

// -------- K1f: fused {1x1 conv 128->64 + L2 norm -> gn}  and  {alpha' = W_sn*alpha} --
__global__ __launch_bounds__(256) void k1f(const float* __restrict__ f,
                                           const float* __restrict__ alpha,
                                           const unsigned* __restrict__ wgb,
                                           const unsigned* __restrict__ wsnb,
                                           const float* __restrict__ bg,
                                           unsigned* __restrict__ gn,
                                           unsigned* __restrict__ apm){
  const int p   = blockIdx.x * 256 + threadIdx.x;
  const int b   = p >> 18;
  const int pix = p & (HWc - 1);
  const float* fb = f + (size_t)b * CGc * HWc + pix;

  // ---- gn = normalize(Wg f + bg) ----
  float acc[CHc];
  #pragma unroll
  for (int o = 0; o < CHc; o++) acc[o] = bg[o];

  #pragma unroll 1
  for (int pp = 0; pp < 64; pp += 4){
    unsigned fp[4];
    #pragma unroll
    for (int m = 0; m < 4; m++)
      fp[m] = pkh(fb[(size_t)(2*(pp+m)) * HWc], fb[(size_t)(2*(pp+m)+1) * HWc]);
    #pragma unroll
    for (int o = 0; o < CHc; o++){
      float a = acc[o];
      a = dot2h(fp[0], wgb[o*64 + pp + 0], a);
      a = dot2h(fp[1], wgb[o*64 + pp + 1], a);
      a = dot2h(fp[2], wgb[o*64 + pp + 2], a);
      a = dot2h(fp[3], wgb[o*64 + pp + 3], a);
      acc[o] = a;
    }
  }
  float nsq = 0.f;
  #pragma unroll
  for (int o = 0; o < CHc; o++) nsq = fmaf(acc[o], acc[o], nsq);
  const float inv = 1.f / fmaxf(sqrtf(nsq), 1e-4f);

  uint4* gp = (uint4*)(gn + (size_t)p * 32);
  #pragma unroll
  for (int k = 0; k < 8; k++){
    uint4 w;
    w.x = pkh(acc[8*k+0]*inv, acc[8*k+1]*inv);
    w.y = pkh(acc[8*k+2]*inv, acc[8*k+3]*inv);
    w.z = pkh(acc[8*k+4]*inv, acc[8*k+5]*inv);
    w.w = pkh(acc[8*k+6]*inv, acc[8*k+7]*inv);
    gp[k] = w;
  }

  // ---- apm = f16(W_sn * alpha), pixel-major ----
  const float* ab = alpha + (size_t)b * COc * HWc + pix;
  unsigned a16[16];
  #pragma unroll
  for (int k = 0; k < 16; k++)
    a16[k] = pkh(ab[(size_t)(2*k) * HWc], ab[(size_t)(2*k+1) * HWc]);
  unsigned ow[16];
  #pragma unroll
  for (int o = 0; o < COc; o += 2){
    float s0 = 0.f, s1 = 0.f;
    #pragma unroll
    for (int k = 0; k < 16; k++){
      s0 = dot2h(a16[k], wsnb[(o+0)*16 + k], s0);
      s1 = dot2h(a16[k], wsnb[(o+1)*16 + k], s1);
    }
    ow[o >> 1] = pkh(s0, s1);
  }
  uint4* op = (uint4*)(apm + (size_t)p * 16);
  #pragma unroll
  for (int k = 0; k < 4; k++)
    op[k] = make_uint4(ow[4*k], ow[4*k+1], ow[4*k+2], ow[4*k+3]);
}

// -------- K2: single-phase correlation + softmax + agg -> y2 f16 (R5 structure) ------
__global__ __launch_bounds__(256) void k2_agg(const unsigned* __restrict__ gn,
                                              const unsigned* __restrict__ apm,
                                              unsigned* __restrict__ y2){
  __shared__ uint4 gs4[8][HPX];   // 68 KB: full halo, 8 channel-pair planes

  const int lb  = (blockIdx.x & 7) * 256 + (blockIdx.x >> 3);   // XCD-chunked swizzle
  const int txx = lb & 15;
  const int tyy = (lb >> 4) & 63;
  const int bb  = lb >> 10;
  const int x0  = txx * TW, y0 = tyy * TH;
  const int tid = threadIdx.x;

  for (int t = tid; t < HPX; t += 256){
    const int hr = t / HLW;
    const int hc = t - hr * HLW;
    const int gy = refl(y0 + hr - 3);
    const int gx = refl(x0 + hc - 3);
    const uint4* src = (const uint4*)(gn + (size_t)((bb << 18) + (gy << 9) + gx) * 32);
    #pragma unroll
    for (int k = 0; k < 8; k++) gs4[k][t] = src[k];
  }
  __syncthreads();

  const int r  = tid >> 5, c = tid & 31;
  const int yy = y0 + r,  xx = x0 + c;
  const int self = (r + 3) * HLW + (c + 3);

  uint4 cv[8];
  #pragma unroll
  for (int k = 0; k < 8; k++) cv[k] = gs4[k][self];

  int ax[7];
  #pragma unroll
  for (int j = 0; j < 7; j++) ax[j] = refl(xx + j - 3);

  float yac[COc];
  #pragma unroll
  for (int k = 0; k < COc; k++) yac[k] = 0.f;
  float esum = 0.f;

  #pragma unroll 1
  for (int i = 0; i < 7; i++){
    const int ay = refl(yy + i - 3);
    const unsigned* aprow = apm + (size_t)((bb << 18) + (ay << 9)) * 16;
    const int rowbase = (r + i) * HLW + c;
    #pragma unroll
    for (int j = 0; j < 7; j++){
      if (i == 3 && j == 3) continue;          // center tap: exp(-10000) == 0
      const int hp = rowbase + j;
      float s0 = 0.f, s1 = 0.f, s2 = 0.f, s3 = 0.f;
      #pragma unroll
      for (int k = 0; k < 8; k++){
        const uint4 q = gs4[k][hp];
        s0 = dot2h(cv[k].x, q.x, s0);
        s1 = dot2h(cv[k].y, q.y, s1);
        s2 = dot2h(cv[k].z, q.z, s2);
        s3 = dot2h(cv[k].w, q.w, s3);
      }
      // |s|<=~1 (unit vectors): exp(s) directly == softmax with max folded out
      const float e = __expf((s0 + s1) + (s2 + s3));
      esum += e;
      const uint4* ap = (const uint4*)(aprow + (size_t)ax[j] * 16);
      #pragma unroll
      for (int kk = 0; kk < 4; kk++){
        const uint4 a = ap[kk];
        mixlo(yac[8*kk+0], a.x, e); mixhi(yac[8*kk+1], a.x, e);
        mixlo(yac[8*kk+2], a.y, e); mixhi(yac[8*kk+3], a.y, e);
        mixlo(yac[8*kk+4], a.z, e); mixhi(yac[8*kk+5], a.z, e);
        mixlo(yac[8*kk+6], a.w, e); mixhi(yac[8*kk+7], a.w, e);
      }
    }
  }

  const float inv = 1.f / esum;
  unsigned yw[16];
  #pragma unroll
  for (int k = 0; k < 16; k++) yw[k] = pkh(yac[2*k] * inv, yac[2*k+1] * inv);
  uint4* yp = (uint4*)(y2 + (size_t)((bb << 18) + (yy << 9) + xx) * 16);
  #pragma unroll
  for (int k = 0; k < 4; k++)
    yp[k] = make_uint4(yw[4*k], yw[4*k+1], yw[4*k+2], yw[4*k+3]);
}

// -------- K3: BN stats over f16 y2 ---------------------------------------------------
__global__ __launch_bounds__(256) void k3_stats(const unsigned* __restrict__ y2,
                                                float* __restrict__ stats){
  float s[COc], q[COc];
  #pragma unroll
  for (int o = 0; o < COc; o++){ s[o] = 0.f; q[o] = 0.f; }
  const int stride = gridDim.x * 256;
  for (int p = blockIdx.x * 256 + threadIdx.x; p < NPIXc; p += stride){
    const uint4* yp = (const uint4*)(y2 + (size_t)p * 16);
    #pragma unroll
    for (int k = 0; k < 4; k++){
      const uint4 w = yp[k];
      const unsigned vv[4] = {w.x, w.y, w.z, w.w};
      #pragma unroll
      for (int m = 0; m < 4; m++){
        const float2 ab = upk(vv[m]);
        s[8*k+2*m]   += ab.x; q[8*k+2*m]   = fmaf(ab.x, ab.x, q[8*k+2*m]);
        s[8*k+2*m+1] += ab.y; q[8*k+2*m+1] = fmaf(ab.y, ab.y, q[8*k+2*m+1]);
      }
    }
  }
  #pragma unroll
  for (int o = 0; o < COc; o++){
    #pragma unroll
    for (int off = 32; off; off >>= 1){
      s[o] += __shfl_down(s[o], off);
      q[o] += __shfl_down(q[o], off);
    }
  }
  __shared__ float red[4][64];
  const int wv = threadIdx.x >> 6;
  if ((threadIdx.x & 63) == 0){
    #pragma unroll
    for (int o = 0; o < COc; o++){ red[wv][o] = s[o]; red[wv][32 + o] = q[o]; }
  }
  __syncthreads();
  if (threadIdx.x < 64){
    const float v = red[0][threadIdx.x] + red[1][threadIdx.x]
                  + red[2][threadIdx.x] + red[3][threadIdx.x];
    atomicAdd(&stats[threadIdx.x], v);
  }
}

// -------- K3b: stats -> (mean, 0.1*rsqrt(var+eps)) ------------------------------------
__global__ void k3b_final(const float* __restrict__ stats, float* __restrict__ stats2){
  const int t = threadIdx.x;
  if (t < COc){
    const float invN = 1.f / (float)NPIXc;
    const float mean = stats[t] * invN;
    const float var  = fmaf(-mean, mean, stats[COc + t] * invN);
    stats2[t]       = mean;
    stats2[COc + t] = 0.1f * rsqrtf(var + 1e-5f);
  }
}

// -------- K4: BatchNorm + residual ----------------------------------------------------
__global__ __launch_bounds__(256) void k4_out(const unsigned* __restrict__ y2,
                                              const float* __restrict__ alpha,
                                              const float* __restrict__ stats2,
                                              float* __restrict__ out){
  const int p   = blockIdx.x * 256 + threadIdx.x;
  const int b   = p >> 18;
  const int pix = p & (HWc - 1);
  const uint4* yp = (const uint4*)(y2 + (size_t)p * 16);
  const size_t boff = (size_t)b * COc * HWc + pix;
  #pragma unroll
  for (int k = 0; k < 4; k++){
    const uint4 w = yp[k];
    const unsigned vv[4] = {w.x, w.y, w.z, w.w};
    #pragma unroll
    for (int m = 0; m < 4; m++){
      const int o = 8*k + 2*m;
      const float2 ab = upk(vv[m]);
      out[boff + (size_t)o*HWc]     = fmaf(ab.x - stats2[o],   stats2[COc+o],
                                           alpha[boff + (size_t)o*HWc]);
      out[boff + (size_t)(o+1)*HWc] = fmaf(ab.y - stats2[o+1], stats2[COc+o+1],
                                           alpha[boff + (size_t)(o+1)*HWc]);
    }
  }
}

extern "C" void kernel_launch(void* const* d_in, const int* in_sizes, int n_in,
                              void* d_out, int out_size, void* d_ws, size_t ws_size,
                              hipStream_t stream){
  const float* f     = (const float*)d_in[0];
  const float* alpha = (const float*)d_in[1];
  const float* wg    = (const float*)d_in[2];
  const float* bg    = (const float*)d_in[3];
  const float* wbar  = (const float*)d_in[4];
  const float* u     = (const float*)d_in[5];
  (void)in_sizes; (void)n_in; (void)out_size; (void)ws_size;
  float* out = (float*)d_out;

  char* ws = (char*)d_ws;
  float*    stats  = (float*)ws;                       // 256 B
  float*    stats2 = (float*)(ws + 4096);              // 256 B
  unsigned* wsnb   = (unsigned*)(ws + 8192);           // 2 KB
  unsigned* wgb    = (unsigned*)(ws + 16384);          // 16 KB
  unsigned* apm    = (unsigned*)(ws + 65536);                                   // 32 MB
  unsigned* gn     = (unsigned*)(ws + 65536 + (size_t)NPIXc*64);                // 64 MB
  unsigned* y2     = (unsigned*)(ws + 65536 + (size_t)NPIXc*64 + (size_t)NPIXc*128); // 32 MB

  hipMemsetAsync(stats, 0, 64 * sizeof(float), stream);
  k0_prep  <<<1, 64, 0, stream>>>(wbar, u, wg, wsnb, wgb);
  k1f      <<<NPIXc / 256, 256, 0, stream>>>(f, alpha, wgb, wsnb, bg, gn, apm);
  k2_agg   <<<2048, 256, 0, stream>>>(gn, apm, y2);
  k3_stats <<<256, 256, 0, stream>>>(y2, stats);
  k3b_final<<<1, 64, 0, stream>>>(stats, stats2);
  k4_out   <<<NPIXc / 256, 256, 0, stream>>>(y2, alpha, stats2, out);
}

// Round 10
// 326.257 us; speedup vs baseline: 1.8087x; 1.0063x over previous
//
#include <hip/hip_runtime.h>

#define HWc   262144   // 512*512
#define CGc   128
#define CHc   64
#define COc   32
#define NPIXc 524288   // B*H*W
#define TW 32
#define TH 8
#define HLW 38         // TW+6
#define HLH 14         // TH+6
#define HPX (HLW*HLH)  // 532

typedef _Float16 h2    __attribute__((ext_vector_type(2)));
typedef __fp16   fp2   __attribute__((ext_vector_type(2)));
typedef _Float16 f16x8 __attribute__((ext_vector_type(8)));
typedef float    f32x4 __attribute__((ext_vector_type(4)));

union AB { uint4 q; f16x8 v; h2 p[4]; unsigned u[4]; };

__device__ __forceinline__ int refl(int p){
  if (p < 0) p = -p;
  else if (p >= 512) p = 1022 - p;
  return p;
}
__device__ __forceinline__ h2 as_h2(unsigned u){ union{unsigned u; h2 h;} x; x.u = u; return x.h; }
__device__ __forceinline__ unsigned as_u(h2 h){ union{unsigned u; h2 h;} x; x.h = h; return x.u; }
__device__ __forceinline__ unsigned pkh(float a, float b){       // RNE pack
  h2 h; h.x = (_Float16)a; h.y = (_Float16)b; return as_u(h);
}
// v_cvt_pkrtz_f16_f32, bit-cast __fp16x2 -> _Float16x2
__device__ __forceinline__ h2 pkrtz(float a, float b){
  union{ fp2 f; h2 h; } x; x.f = __builtin_amdgcn_cvt_pkrtz(a, b); return x.h;
}
__device__ __forceinline__ float2 upk(unsigned u){
  h2 h = as_h2(u); return make_float2((float)h.x, (float)h.y);
}
__device__ __forceinline__ float dot2h(unsigned a, unsigned b, float c){
  return __builtin_amdgcn_fdot2(as_h2(a), as_h2(b), c, false);
}
__device__ __forceinline__ void mixlo(float& acc, unsigned ab, float e){
  asm("v_fma_mix_f32 %0, %1, %2, %0 op_sel:[0,0,0] op_sel_hi:[1,0,0]"
      : "+v"(acc) : "v"(ab), "v"(e));
}
__device__ __forceinline__ void mixhi(float& acc, unsigned ab, float e){
  asm("v_fma_mix_f32 %0, %1, %2, %0 op_sel:[1,0,0] op_sel_hi:[1,0,0]"
      : "+v"(acc) : "v"(ab), "v"(e));
}

// -------- K0: sigma; pack wg and w_sn into MFMA A-fragment order ----------------------
// A-frag convention (16x16x32 f16): lane L holds row o = L&15, k = 8*(L>>4)+e, e=0..7.
__global__ void k0_prep(const float* __restrict__ wbar, const float* __restrict__ u,
                        const float* __restrict__ wg,
                        unsigned* __restrict__ wgA, unsigned* __restrict__ wsnA){
  const int t = threadIdx.x;
  __shared__ float sv1[32];
  float tv = 0.f;
  if (t < 32){
    #pragma unroll
    for (int o = 0; o < 32; o++) tv += wbar[o*32 + t] * u[o];
  }
  float sq = tv * tv;
  #pragma unroll
  for (int off = 32; off; off >>= 1) sq += __shfl_down(sq, off);
  const float n1 = sqrtf(__shfl(sq, 0)) + 1e-12f;
  if (t < 32) sv1[t] = tv / n1;
  __syncthreads();
  float tu = 0.f;
  if (t < 32){
    #pragma unroll
    for (int c = 0; c < 32; c++) tu += wbar[t*32 + c] * sv1[c];
  }
  float sq2 = tu * tu;
  #pragma unroll
  for (int off = 32; off; off >>= 1) sq2 += __shfl_down(sq2, off);
  const float S = __shfl(sq2, 0);
  const float inv = (sqrtf(S) + 1e-12f) / S;     // 1/sigma

  // wgA[((m*4+ks)*64 + L)*4 + j]: pair (2j,2j+1) of the 8 k-elems
  for (int k = t; k < 4096; k += 64){
    const int mk = k >> 8, L = (k >> 2) & 63, j = k & 3;
    const int m = mk >> 2, ks = mk & 3;
    const int o = m*16 + (L & 15);
    const int c = ks*32 + 8*(L >> 4) + 2*j;
    wgA[k] = pkh(wg[o*128 + c], wg[o*128 + c + 1]);
  }
  // wsnA[(m*64 + L)*4 + j], K=32 single k-step
  for (int k = t; k < 512; k += 64){
    const int m = k >> 8, L = (k >> 2) & 63, j = k & 3;
    const int o = m*16 + (L & 15);
    const int c = 8*(L >> 4) + 2*j;
    wsnA[k] = pkh(wbar[o*32 + c] * inv, wbar[o*32 + c + 1] * inv);
  }
}

// -------- K1m: MFMA {1x1 conv 128->64 + L2 norm -> gn} and {alpha' = W_sn*alpha} -----
__global__ __launch_bounds__(256) void k1m(const float* __restrict__ f,
                                           const float* __restrict__ alpha,
                                           const uint4* __restrict__ wgA,
                                           const uint4* __restrict__ wsnA,
                                           const float* __restrict__ bg,
                                           unsigned* __restrict__ gn,
                                           unsigned* __restrict__ apm){
  const int tid  = threadIdx.x;
  const int lane = tid & 63, w = tid >> 6;
  const int lo   = lane & 15, hi = lane >> 4;

  AB wga[4][4];
  #pragma unroll
  for (int m = 0; m < 4; m++)
    #pragma unroll
    for (int ks = 0; ks < 4; ks++)
      wga[m][ks].q = wgA[(m*4 + ks)*64 + lane];
  AB wsa[2];
  #pragma unroll
  for (int m = 0; m < 2; m++) wsa[m].q = wsnA[m*64 + lane];
  float4 bgl[4];
  #pragma unroll
  for (int m = 0; m < 4; m++) bgl[m] = *(const float4*)(bg + m*16 + hi*4);

  const int pxg = blockIdx.x * 256 + w * 64;

  #pragma unroll 1
  for (int nt = 0; nt < 4; nt++){
    const int px0  = pxg + nt*16;
    const int b    = px0 >> 18;
    const int pix0 = px0 & (HWc - 1);
    const float* fb = f + (size_t)b * CGc * HWc + pix0 + lo;

    f32x4 acc[4];
    #pragma unroll
    for (int m = 0; m < 4; m++) acc[m] = (f32x4){0.f, 0.f, 0.f, 0.f};

    #pragma unroll
    for (int ks = 0; ks < 4; ks++){
      const float* fc = fb + (size_t)(ks*32 + hi*8) * HWc;
      AB bf;
      #pragma unroll
      for (int j = 0; j < 4; j++)
        bf.p[j] = pkrtz(fc[(size_t)(2*j) * HWc], fc[(size_t)(2*j + 1) * HWc]);
      #pragma unroll
      for (int m = 0; m < 4; m++)
        acc[m] = __builtin_amdgcn_mfma_f32_16x16x32_f16(wga[m][ks].v, bf.v, acc[m], 0, 0, 0);
    }

    // bias + per-pixel L2 norm (64 ch of px(lo) live in lanes lo, lo+16, lo+32, lo+48)
    float v[16]; float nsq = 0.f;
    #pragma unroll
    for (int m = 0; m < 4; m++){
      v[4*m+0] = acc[m][0] + bgl[m].x;
      v[4*m+1] = acc[m][1] + bgl[m].y;
      v[4*m+2] = acc[m][2] + bgl[m].z;
      v[4*m+3] = acc[m][3] + bgl[m].w;
      nsq = fmaf(v[4*m+0], v[4*m+0], nsq); nsq = fmaf(v[4*m+1], v[4*m+1], nsq);
      nsq = fmaf(v[4*m+2], v[4*m+2], nsq); nsq = fmaf(v[4*m+3], v[4*m+3], nsq);
    }
    nsq += __shfl_xor(nsq, 16);
    nsq += __shfl_xor(nsq, 32);
    const float inv = 1.f / fmaxf(sqrtf(nsq), 1e-4f);

    unsigned* gp = gn + (size_t)(px0 + lo) * 32 + hi*2;
    #pragma unroll
    for (int m = 0; m < 4; m++){
      uint2 st = make_uint2(pkh(v[4*m+0]*inv, v[4*m+1]*inv),
                            pkh(v[4*m+2]*inv, v[4*m+3]*inv));
      *(uint2*)(gp + m*8) = st;
    }

    // alpha' = W_sn * alpha (K=32, 2 M-tiles)
    const float* ac = alpha + (size_t)b * COc * HWc + pix0 + lo + (size_t)(hi*8) * HWc;
    AB af;
    #pragma unroll
    for (int j = 0; j < 4; j++)
      af.p[j] = pkrtz(ac[(size_t)(2*j) * HWc], ac[(size_t)(2*j + 1) * HWc]);
    unsigned* op = apm + (size_t)(px0 + lo) * 16 + hi*2;
    #pragma unroll
    for (int m = 0; m < 2; m++){
      f32x4 aa = (f32x4){0.f, 0.f, 0.f, 0.f};
      aa = __builtin_amdgcn_mfma_f32_16x16x32_f16(wsa[m].v, af.v, aa, 0, 0, 0);
      uint2 st = make_uint2(pkh(aa[0], aa[1]), pkh(aa[2], aa[3]));
      *(uint2*)(op + m*8) = st;
    }
  }
}

// -------- K2: single-phase correlation + softmax + agg -> y2 f16 (R8, proven) --------
__global__ __launch_bounds__(256) void k2_agg(const unsigned* __restrict__ gn,
                                              const unsigned* __restrict__ apm,
                                              unsigned* __restrict__ y2){
  __shared__ uint4 gs4[8][HPX];   // 68 KB: full halo, 8 channel-pair planes

  const int lb  = (blockIdx.x & 7) * 256 + (blockIdx.x >> 3);   // XCD-chunked swizzle
  const int txx = lb & 15;
  const int tyy = (lb >> 4) & 63;
  const int bb  = lb >> 10;
  const int x0  = txx * TW, y0 = tyy * TH;
  const int tid = threadIdx.x;

  for (int t = tid; t < HPX; t += 256){
    const int hr = t / HLW;
    const int hc = t - hr * HLW;
    const int gy = refl(y0 + hr - 3);
    const int gx = refl(x0 + hc - 3);
    const uint4* src = (const uint4*)(gn + (size_t)((bb << 18) + (gy << 9) + gx) * 32);
    #pragma unroll
    for (int k = 0; k < 8; k++) gs4[k][t] = src[k];
  }
  __syncthreads();

  const int r  = tid >> 5, c = tid & 31;
  const int yy = y0 + r,  xx = x0 + c;
  const int self = (r + 3) * HLW + (c + 3);

  uint4 cv[8];
  #pragma unroll
  for (int k = 0; k < 8; k++) cv[k] = gs4[k][self];

  int ax[7];
  #pragma unroll
  for (int j = 0; j < 7; j++) ax[j] = refl(xx + j - 3);

  float yac[COc];
  #pragma unroll
  for (int k = 0; k < COc; k++) yac[k] = 0.f;
  float esum = 0.f;

  #pragma unroll 1
  for (int i = 0; i < 7; i++){
    const int ay = refl(yy + i - 3);
    const unsigned* aprow = apm + (size_t)((bb << 18) + (ay << 9)) * 16;
    const int rowbase = (r + i) * HLW + c;
    #pragma unroll
    for (int j = 0; j < 7; j++){
      if (i == 3 && j == 3) continue;          // center tap: exp(-10000) == 0
      const int hp = rowbase + j;
      float s0 = 0.f, s1 = 0.f, s2 = 0.f, s3 = 0.f;
      #pragma unroll
      for (int k = 0; k < 8; k++){
        const uint4 q = gs4[k][hp];
        s0 = dot2h(cv[k].x, q.x, s0);
        s1 = dot2h(cv[k].y, q.y, s1);
        s2 = dot2h(cv[k].z, q.z, s2);
        s3 = dot2h(cv[k].w, q.w, s3);
      }
      const float e = __expf((s0 + s1) + (s2 + s3));
      esum += e;
      const uint4* ap = (const uint4*)(aprow + (size_t)ax[j] * 16);
      #pragma unroll
      for (int kk = 0; kk < 4; kk++){
        const uint4 a = ap[kk];
        mixlo(yac[8*kk+0], a.x, e); mixhi(yac[8*kk+1], a.x, e);
        mixlo(yac[8*kk+2], a.y, e); mixhi(yac[8*kk+3], a.y, e);
        mixlo(yac[8*kk+4], a.z, e); mixhi(yac[8*kk+5], a.z, e);
        mixlo(yac[8*kk+6], a.w, e); mixhi(yac[8*kk+7], a.w, e);
      }
    }
  }

  const float inv = 1.f / esum;
  unsigned yw[16];
  #pragma unroll
  for (int k = 0; k < 16; k++) yw[k] = pkh(yac[2*k] * inv, yac[2*k+1] * inv);
  uint4* yp = (uint4*)(y2 + (size_t)((bb << 18) + (yy << 9) + xx) * 16);
  #pragma unroll
  for (int k = 0; k < 4; k++)
    yp[k] = make_uint4(yw[4*k], yw[4*k+1], yw[4*k+2], yw[4*k+3]);
}

// -------- K3: BN stats over f16 y2 ---------------------------------------------------
__global__ __launch_bounds__(256) void k3_stats(const unsigned* __restrict__ y2,
                                                float* __restrict__ stats){
  float s[COc], q[COc];
  #pragma unroll
  for (int o = 0; o < COc; o++){ s[o] = 0.f; q[o] = 0.f; }
  const int stride = gridDim.x * 256;
  for (int p = blockIdx.x * 256 + threadIdx.x; p < NPIXc; p += stride){
    const uint4* yp = (const uint4*)(y2 + (size_t)p * 16);
    #pragma unroll
    for (int k = 0; k < 4; k++){
      const uint4 w = yp[k];
      const unsigned vv[4] = {w.x, w.y, w.z, w.w};
      #pragma unroll
      for (int m = 0; m < 4; m++){
        const float2 ab = upk(vv[m]);
        s[8*k+2*m]   += ab.x; q[8*k+2*m]   = fmaf(ab.x, ab.x, q[8*k+2*m]);
        s[8*k+2*m+1] += ab.y; q[8*k+2*m+1] = fmaf(ab.y, ab.y, q[8*k+2*m+1]);
      }
    }
  }
  #pragma unroll
  for (int o = 0; o < COc; o++){
    #pragma unroll
    for (int off = 32; off; off >>= 1){
      s[o] += __shfl_down(s[o], off);
      q[o] += __shfl_down(q[o], off);
    }
  }
  __shared__ float red[4][64];
  const int wv = threadIdx.x >> 6;
  if ((threadIdx.x & 63) == 0){
    #pragma unroll
    for (int o = 0; o < COc; o++){ red[wv][o] = s[o]; red[wv][32 + o] = q[o]; }
  }
  __syncthreads();
  if (threadIdx.x < 64){
    const float v = red[0][threadIdx.x] + red[1][threadIdx.x]
                  + red[2][threadIdx.x] + red[3][threadIdx.x];
    atomicAdd(&stats[threadIdx.x], v);
  }
}

// -------- K3b: stats -> (mean, 0.1*rsqrt(var+eps)) ------------------------------------
__global__ void k3b_final(const float* __restrict__ stats, float* __restrict__ stats2){
  const int t = threadIdx.x;
  if (t < COc){
    const float invN = 1.f / (float)NPIXc;
    const float mean = stats[t] * invN;
    const float var  = fmaf(-mean, mean, stats[COc + t] * invN);
    stats2[t]       = mean;
    stats2[COc + t] = 0.1f * rsqrtf(var + 1e-5f);
  }
}

// -------- K4: BatchNorm + residual ----------------------------------------------------
__global__ __launch_bounds__(256) void k4_out(const unsigned* __restrict__ y2,
                                              const float* __restrict__ alpha,
                                              const float* __restrict__ stats2,
                                              float* __restrict__ out){
  const int p   = blockIdx.x * 256 + threadIdx.x;
  const int b   = p >> 18;
  const int pix = p & (HWc - 1);
  const uint4* yp = (const uint4*)(y2 + (size_t)p * 16);
  const size_t boff = (size_t)b * COc * HWc + pix;
  #pragma unroll
  for (int k = 0; k < 4; k++){
    const uint4 w = yp[k];
    const unsigned vv[4] = {w.x, w.y, w.z, w.w};
    #pragma unroll
    for (int m = 0; m < 4; m++){
      const int o = 8*k + 2*m;
      const float2 ab = upk(vv[m]);
      out[boff + (size_t)o*HWc]     = fmaf(ab.x - stats2[o],   stats2[COc+o],
                                           alpha[boff + (size_t)o*HWc]);
      out[boff + (size_t)(o+1)*HWc] = fmaf(ab.y - stats2[o+1], stats2[COc+o+1],
                                           alpha[boff + (size_t)(o+1)*HWc]);
    }
  }
}

extern "C" void kernel_launch(void* const* d_in, const int* in_sizes, int n_in,
                              void* d_out, int out_size, void* d_ws, size_t ws_size,
                              hipStream_t stream){
  const float* f     = (const float*)d_in[0];
  const float* alpha = (const float*)d_in[1];
  const float* wg    = (const float*)d_in[2];
  const float* bg    = (const float*)d_in[3];
  const float* wbar  = (const float*)d_in[4];
  const float* u     = (const float*)d_in[5];
  (void)in_sizes; (void)n_in; (void)out_size; (void)ws_size;
  float* out = (float*)d_out;

  char* ws = (char*)d_ws;
  float*    stats  = (float*)ws;                       // 256 B
  float*    stats2 = (float*)(ws + 4096);              // 256 B
  unsigned* wgA    = (unsigned*)(ws + 8192);           // 16 KB (MFMA A-frag order)
  unsigned* wsnA   = (unsigned*)(ws + 32768);          // 2 KB
  unsigned* apm    = (unsigned*)(ws + 65536);                                   // 32 MB
  unsigned* gn     = (unsigned*)(ws + 65536 + (size_t)NPIXc*64);                // 64 MB
  unsigned* y2     = (unsigned*)(ws + 65536 + (size_t)NPIXc*64 + (size_t)NPIXc*128); // 32 MB

  (void)hipMemsetAsync(stats, 0, 64 * sizeof(float), stream);
  k0_prep  <<<1, 64, 0, stream>>>(wbar, u, wg, wgA, wsnA);
  k1m      <<<NPIXc / 256, 256, 0, stream>>>(f, alpha, (const uint4*)wgA,
                                             (const uint4*)wsnA, bg, gn, apm);
  k2_agg   <<<2048, 256, 0, stream>>>(gn, apm, y2);
  k3_stats <<<256, 256, 0, stream>>>(y2, stats);
  k3b_final<<<1, 64, 0, stream>>>(stats, stats2);
  k4_out   <<<NPIXc / 256, 256, 0, stream>>>(y2, alpha, stats2, out);
}

// Round 11
// 318.481 us; speedup vs baseline: 1.8529x; 1.0244x over previous
//
#include <hip/hip_runtime.h>

#define HWc   262144   // 512*512
#define CGc   128
#define CHc   64
#define COc   32
#define NPIXc 524288   // B*H*W
#define TW 32
#define TH 8
#define HLW 38         // TW+6
#define HLH 14         // TH+6
#define HPX (HLW*HLH)  // 532

typedef _Float16 h2    __attribute__((ext_vector_type(2)));
typedef __fp16   fp2   __attribute__((ext_vector_type(2)));
typedef _Float16 f16x8 __attribute__((ext_vector_type(8)));
typedef float    f32x4 __attribute__((ext_vector_type(4)));

union AB { uint4 q; f16x8 v; h2 p[4]; unsigned u[4]; };

__device__ __forceinline__ int refl(int p){
  if (p < 0) p = -p;
  else if (p >= 512) p = 1022 - p;
  return p;
}
__device__ __forceinline__ h2 as_h2(unsigned u){ union{unsigned u; h2 h;} x; x.u = u; return x.h; }
__device__ __forceinline__ unsigned as_u(h2 h){ union{unsigned u; h2 h;} x; x.h = h; return x.u; }
__device__ __forceinline__ unsigned pkh(float a, float b){       // RNE pack
  h2 h; h.x = (_Float16)a; h.y = (_Float16)b; return as_u(h);
}
// v_cvt_pkrtz_f16_f32, bit-cast __fp16x2 -> _Float16x2
__device__ __forceinline__ h2 pkrtz(float a, float b){
  union{ fp2 f; h2 h; } x; x.f = __builtin_amdgcn_cvt_pkrtz(a, b); return x.h;
}
__device__ __forceinline__ float2 upk(unsigned u){
  h2 h = as_h2(u); return make_float2((float)h.x, (float)h.y);
}
__device__ __forceinline__ float dot2h(unsigned a, unsigned b, float c){
  return __builtin_amdgcn_fdot2(as_h2(a), as_h2(b), c, false);
}
__device__ __forceinline__ void mixlo(float& acc, unsigned ab, float e){
  asm("v_fma_mix_f32 %0, %1, %2, %0 op_sel:[0,0,0] op_sel_hi:[1,0,0]"
      : "+v"(acc) : "v"(ab), "v"(e));
}
__device__ __forceinline__ void mixhi(float& acc, unsigned ab, float e){
  asm("v_fma_mix_f32 %0, %1, %2, %0 op_sel:[1,0,0] op_sel_hi:[1,0,0]"
      : "+v"(acc) : "v"(ab), "v"(e));
}

// -------- K0: sigma; pack wg and w_sn into MFMA A-fragment order ----------------------
// A-frag convention (16x16x32 f16): lane L holds row o = L&15, k = 8*(L>>4)+e, e=0..7.
__global__ void k0_prep(const float* __restrict__ wbar, const float* __restrict__ u,
                        const float* __restrict__ wg,
                        unsigned* __restrict__ wgA, unsigned* __restrict__ wsnA){
  const int t = threadIdx.x;
  __shared__ float sv1[32];
  float tv = 0.f;
  if (t < 32){
    #pragma unroll
    for (int o = 0; o < 32; o++) tv += wbar[o*32 + t] * u[o];
  }
  float sq = tv * tv;
  #pragma unroll
  for (int off = 32; off; off >>= 1) sq += __shfl_down(sq, off);
  const float n1 = sqrtf(__shfl(sq, 0)) + 1e-12f;
  if (t < 32) sv1[t] = tv / n1;
  __syncthreads();
  float tu = 0.f;
  if (t < 32){
    #pragma unroll
    for (int c = 0; c < 32; c++) tu += wbar[t*32 + c] * sv1[c];
  }
  float sq2 = tu * tu;
  #pragma unroll
  for (int off = 32; off; off >>= 1) sq2 += __shfl_down(sq2, off);
  const float S = __shfl(sq2, 0);
  const float inv = (sqrtf(S) + 1e-12f) / S;     // 1/sigma

  // wgA[((m*4+ks)*64 + L)*4 + j]: pair (2j,2j+1) of the 8 k-elems
  for (int k = t; k < 4096; k += 64){
    const int mk = k >> 8, L = (k >> 2) & 63, j = k & 3;
    const int m = mk >> 2, ks = mk & 3;
    const int o = m*16 + (L & 15);
    const int c = ks*32 + 8*(L >> 4) + 2*j;
    wgA[k] = pkh(wg[o*128 + c], wg[o*128 + c + 1]);
  }
  // wsnA[(m*64 + L)*4 + j], K=32 single k-step
  for (int k = t; k < 512; k += 64){
    const int m = k >> 8, L = (k >> 2) & 63, j = k & 3;
    const int o = m*16 + (L & 15);
    const int c = 8*(L >> 4) + 2*j;
    wsnA[k] = pkh(wbar[o*32 + c] * inv, wbar[o*32 + c + 1] * inv);
  }
}

// -------- K1m: MFMA {1x1 conv 128->64 + L2 norm -> gn} and {alpha' = W_sn*alpha} -----
// R11: batch ALL global loads per tile into register arrays BEFORE converts/MFMAs,
// breaking the compiler's load->cvt serialization (R10: VGPR=88 => ~2-deep MLP).
__global__ __launch_bounds__(256) void k1m(const float* __restrict__ f,
                                           const float* __restrict__ alpha,
                                           const uint4* __restrict__ wgA,
                                           const uint4* __restrict__ wsnA,
                                           const float* __restrict__ bg,
                                           unsigned* __restrict__ gn,
                                           unsigned* __restrict__ apm){
  const int tid  = threadIdx.x;
  const int lane = tid & 63, w = tid >> 6;
  const int lo   = lane & 15, hi = lane >> 4;

  AB wga[4][4];
  #pragma unroll
  for (int m = 0; m < 4; m++)
    #pragma unroll
    for (int ks = 0; ks < 4; ks++)
      wga[m][ks].q = wgA[(m*4 + ks)*64 + lane];
  AB wsa[2];
  #pragma unroll
  for (int m = 0; m < 2; m++) wsa[m].q = wsnA[m*64 + lane];
  float4 bgl[4];
  #pragma unroll
  for (int m = 0; m < 4; m++) bgl[m] = *(const float4*)(bg + m*16 + hi*4);

  const int pxg = blockIdx.x * 256 + w * 64;

  #pragma unroll 1
  for (int nt = 0; nt < 4; nt++){
    const int px0  = pxg + nt*16;
    const int b    = px0 >> 18;
    const int pix0 = px0 & (HWc - 1);
    const float* fb = f + (size_t)b * CGc * HWc + pix0 + lo;
    const float* ac = alpha + (size_t)b * COc * HWc + pix0 + lo + (size_t)(hi*8) * HWc;

    // ---- batch-issue all 40 independent loads (40-deep MLP) ----
    float fv[32], av[8];
    #pragma unroll
    for (int ks = 0; ks < 4; ks++){
      const float* fc = fb + (size_t)(ks*32 + hi*8) * HWc;
      #pragma unroll
      for (int e = 0; e < 8; e++)
        fv[ks*8 + e] = fc[(size_t)e * HWc];
    }
    #pragma unroll
    for (int e = 0; e < 8; e++)
      av[e] = ac[(size_t)e * HWc];

    // ---- convert + MFMA ----
    f32x4 acc[4];
    #pragma unroll
    for (int m = 0; m < 4; m++) acc[m] = (f32x4){0.f, 0.f, 0.f, 0.f};

    #pragma unroll
    for (int ks = 0; ks < 4; ks++){
      AB bf;
      #pragma unroll
      for (int j = 0; j < 4; j++)
        bf.p[j] = pkrtz(fv[ks*8 + 2*j], fv[ks*8 + 2*j + 1]);
      #pragma unroll
      for (int m = 0; m < 4; m++)
        acc[m] = __builtin_amdgcn_mfma_f32_16x16x32_f16(wga[m][ks].v, bf.v, acc[m], 0, 0, 0);
    }

    // bias + per-pixel L2 norm (64 ch of px(lo) live in lanes lo, lo+16, lo+32, lo+48)
    float v[16]; float nsq = 0.f;
    #pragma unroll
    for (int m = 0; m < 4; m++){
      v[4*m+0] = acc[m][0] + bgl[m].x;
      v[4*m+1] = acc[m][1] + bgl[m].y;
      v[4*m+2] = acc[m][2] + bgl[m].z;
      v[4*m+3] = acc[m][3] + bgl[m].w;
      nsq = fmaf(v[4*m+0], v[4*m+0], nsq); nsq = fmaf(v[4*m+1], v[4*m+1], nsq);
      nsq = fmaf(v[4*m+2], v[4*m+2], nsq); nsq = fmaf(v[4*m+3], v[4*m+3], nsq);
    }
    nsq += __shfl_xor(nsq, 16);
    nsq += __shfl_xor(nsq, 32);
    const float inv = 1.f / fmaxf(sqrtf(nsq), 1e-4f);

    unsigned* gp = gn + (size_t)(px0 + lo) * 32 + hi*2;
    #pragma unroll
    for (int m = 0; m < 4; m++){
      uint2 st = make_uint2(pkh(v[4*m+0]*inv, v[4*m+1]*inv),
                            pkh(v[4*m+2]*inv, v[4*m+3]*inv));
      *(uint2*)(gp + m*8) = st;
    }

    // alpha' = W_sn * alpha (K=32, 2 M-tiles)
    AB af;
    #pragma unroll
    for (int j = 0; j < 4; j++)
      af.p[j] = pkrtz(av[2*j], av[2*j + 1]);
    unsigned* op = apm + (size_t)(px0 + lo) * 16 + hi*2;
    #pragma unroll
    for (int m = 0; m < 2; m++){
      f32x4 aa = (f32x4){0.f, 0.f, 0.f, 0.f};
      aa = __builtin_amdgcn_mfma_f32_16x16x32_f16(wsa[m].v, af.v, aa, 0, 0, 0);
      uint2 st = make_uint2(pkh(aa[0], aa[1]), pkh(aa[2], aa[3]));
      *(uint2*)(op + m*8) = st;
    }
  }
}

// -------- K2: single-phase correlation + softmax + agg -> y2 f16 (R8, proven) --------
__global__ __launch_bounds__(256) void k2_agg(const unsigned* __restrict__ gn,
                                              const unsigned* __restrict__ apm,
                                              unsigned* __restrict__ y2){
  __shared__ uint4 gs4[8][HPX];   // 68 KB: full halo, 8 channel-pair planes

  const int lb  = (blockIdx.x & 7) * 256 + (blockIdx.x >> 3);   // XCD-chunked swizzle
  const int txx = lb & 15;
  const int tyy = (lb >> 4) & 63;
  const int bb  = lb >> 10;
  const int x0  = txx * TW, y0 = tyy * TH;
  const int tid = threadIdx.x;

  for (int t = tid; t < HPX; t += 256){
    const int hr = t / HLW;
    const int hc = t - hr * HLW;
    const int gy = refl(y0 + hr - 3);
    const int gx = refl(x0 + hc - 3);
    const uint4* src = (const uint4*)(gn + (size_t)((bb << 18) + (gy << 9) + gx) * 32);
    #pragma unroll
    for (int k = 0; k < 8; k++) gs4[k][t] = src[k];
  }
  __syncthreads();

  const int r  = tid >> 5, c = tid & 31;
  const int yy = y0 + r,  xx = x0 + c;
  const int self = (r + 3) * HLW + (c + 3);

  uint4 cv[8];
  #pragma unroll
  for (int k = 0; k < 8; k++) cv[k] = gs4[k][self];

  int ax[7];
  #pragma unroll
  for (int j = 0; j < 7; j++) ax[j] = refl(xx + j - 3);

  float yac[COc];
  #pragma unroll
  for (int k = 0; k < COc; k++) yac[k] = 0.f;
  float esum = 0.f;

  #pragma unroll 1
  for (int i = 0; i < 7; i++){
    const int ay = refl(yy + i - 3);
    const unsigned* aprow = apm + (size_t)((bb << 18) + (ay << 9)) * 16;
    const int rowbase = (r + i) * HLW + c;
    #pragma unroll
    for (int j = 0; j < 7; j++){
      if (i == 3 && j == 3) continue;          // center tap: exp(-10000) == 0
      const int hp = rowbase + j;
      float s0 = 0.f, s1 = 0.f, s2 = 0.f, s3 = 0.f;
      #pragma unroll
      for (int k = 0; k < 8; k++){
        const uint4 q = gs4[k][hp];
        s0 = dot2h(cv[k].x, q.x, s0);
        s1 = dot2h(cv[k].y, q.y, s1);
        s2 = dot2h(cv[k].z, q.z, s2);
        s3 = dot2h(cv[k].w, q.w, s3);
      }
      const float e = __expf((s0 + s1) + (s2 + s3));
      esum += e;
      const uint4* ap = (const uint4*)(aprow + (size_t)ax[j] * 16);
      #pragma unroll
      for (int kk = 0; kk < 4; kk++){
        const uint4 a = ap[kk];
        mixlo(yac[8*kk+0], a.x, e); mixhi(yac[8*kk+1], a.x, e);
        mixlo(yac[8*kk+2], a.y, e); mixhi(yac[8*kk+3], a.y, e);
        mixlo(yac[8*kk+4], a.z, e); mixhi(yac[8*kk+5], a.z, e);
        mixlo(yac[8*kk+6], a.w, e); mixhi(yac[8*kk+7], a.w, e);
      }
    }
  }

  const float inv = 1.f / esum;
  unsigned yw[16];
  #pragma unroll
  for (int k = 0; k < 16; k++) yw[k] = pkh(yac[2*k] * inv, yac[2*k+1] * inv);
  uint4* yp = (uint4*)(y2 + (size_t)((bb << 18) + (yy << 9) + xx) * 16);
  #pragma unroll
  for (int k = 0; k < 4; k++)
    yp[k] = make_uint4(yw[4*k], yw[4*k+1], yw[4*k+2], yw[4*k+3]);
}

// -------- K3: BN stats over f16 y2 ---------------------------------------------------
__global__ __launch_bounds__(256) void k3_stats(const unsigned* __restrict__ y2,
                                                float* __restrict__ stats){
  float s[COc], q[COc];
  #pragma unroll
  for (int o = 0; o < COc; o++){ s[o] = 0.f; q[o] = 0.f; }
  const int stride = gridDim.x * 256;
  for (int p = blockIdx.x * 256 + threadIdx.x; p < NPIXc; p += stride){
    const uint4* yp = (const uint4*)(y2 + (size_t)p * 16);
    #pragma unroll
    for (int k = 0; k < 4; k++){
      const uint4 w = yp[k];
      const unsigned vv[4] = {w.x, w.y, w.z, w.w};
      #pragma unroll
      for (int m = 0; m < 4; m++){
        const float2 ab = upk(vv[m]);
        s[8*k+2*m]   += ab.x; q[8*k+2*m]   = fmaf(ab.x, ab.x, q[8*k+2*m]);
        s[8*k+2*m+1] += ab.y; q[8*k+2*m+1] = fmaf(ab.y, ab.y, q[8*k+2*m+1]);
      }
    }
  }
  #pragma unroll
  for (int o = 0; o < COc; o++){
    #pragma unroll
    for (int off = 32; off; off >>= 1){
      s[o] += __shfl_down(s[o], off);
      q[o] += __shfl_down(q[o], off);
    }
  }
  __shared__ float red[4][64];
  const int wv = threadIdx.x >> 6;
  if ((threadIdx.x & 63) == 0){
    #pragma unroll
    for (int o = 0; o < COc; o++){ red[wv][o] = s[o]; red[wv][32 + o] = q[o]; }
  }
  __syncthreads();
  if (threadIdx.x < 64){
    const float v = red[0][threadIdx.x] + red[1][threadIdx.x]
                  + red[2][threadIdx.x] + red[3][threadIdx.x];
    atomicAdd(&stats[threadIdx.x], v);
  }
}

// -------- K3b: stats -> (mean, 0.1*rsqrt(var+eps)) ------------------------------------
__global__ void k3b_final(const float* __restrict__ stats, float* __restrict__ stats2){
  const int t = threadIdx.x;
  if (t < COc){
    const float invN = 1.f / (float)NPIXc;
    const float mean = stats[t] * invN;
    const float var  = fmaf(-mean, mean, stats[COc + t] * invN);
    stats2[t]       = mean;
    stats2[COc + t] = 0.1f * rsqrtf(var + 1e-5f);
  }
}

// -------- K4: BatchNorm + residual ----------------------------------------------------
__global__ __launch_bounds__(256) void k4_out(const unsigned* __restrict__ y2,
                                              const float* __restrict__ alpha,
                                              const float* __restrict__ stats2,
                                              float* __restrict__ out){
  const int p   = blockIdx.x * 256 + threadIdx.x;
  const int b   = p >> 18;
  const int pix = p & (HWc - 1);
  const uint4* yp = (const uint4*)(y2 + (size_t)p * 16);
  const size_t boff = (size_t)b * COc * HWc + pix;
  #pragma unroll
  for (int k = 0; k < 4; k++){
    const uint4 w = yp[k];
    const unsigned vv[4] = {w.x, w.y, w.z, w.w};
    #pragma unroll
    for (int m = 0; m < 4; m++){
      const int o = 8*k + 2*m;
      const float2 ab = upk(vv[m]);
      out[boff + (size_t)o*HWc]     = fmaf(ab.x - stats2[o],   stats2[COc+o],
                                           alpha[boff + (size_t)o*HWc]);
      out[boff + (size_t)(o+1)*HWc] = fmaf(ab.y - stats2[o+1], stats2[COc+o+1],
                                           alpha[boff + (size_t)(o+1)*HWc]);
    }
  }
}

extern "C" void kernel_launch(void* const* d_in, const int* in_sizes, int n_in,
                              void* d_out, int out_size, void* d_ws, size_t ws_size,
                              hipStream_t stream){
  const float* f     = (const float*)d_in[0];
  const float* alpha = (const float*)d_in[1];
  const float* wg    = (const float*)d_in[2];
  const float* bg    = (const float*)d_in[3];
  const float* wbar  = (const float*)d_in[4];
  const float* u     = (const float*)d_in[5];
  (void)in_sizes; (void)n_in; (void)out_size; (void)ws_size;
  float* out = (float*)d_out;

  char* ws = (char*)d_ws;
  float*    stats  = (float*)ws;                       // 256 B
  float*    stats2 = (float*)(ws + 4096);              // 256 B
  unsigned* wgA    = (unsigned*)(ws + 8192);           // 16 KB (MFMA A-frag order)
  unsigned* wsnA   = (unsigned*)(ws + 32768);          // 2 KB
  unsigned* apm    = (unsigned*)(ws + 65536);                                   // 32 MB
  unsigned* gn     = (unsigned*)(ws + 65536 + (size_t)NPIXc*64);                // 64 MB
  unsigned* y2     = (unsigned*)(ws + 65536 + (size_t)NPIXc*64 + (size_t)NPIXc*128); // 32 MB

  (void)hipMemsetAsync(stats, 0, 64 * sizeof(float), stream);
  k0_prep  <<<1, 64, 0, stream>>>(wbar, u, wg, wgA, wsnA);
  k1m      <<<NPIXc / 256, 256, 0, stream>>>(f, alpha, (const uint4*)wgA,
                                             (const uint4*)wsnA, bg, gn, apm);
  k2_agg   <<<2048, 256, 0, stream>>>(gn, apm, y2);
  k3_stats <<<256, 256, 0, stream>>>(y2, stats);
  k3b_final<<<1, 64, 0, stream>>>(stats, stats2);
  k4_out   <<<NPIXc / 256, 256, 0, stream>>>(y2, alpha, stats2, out);
}